// Round 4
// baseline (579.797 us; speedup 1.0000x reference)
//
#include <hip/hip_runtime.h>
#include <hip/hip_bf16.h>
#include <math.h>

#define N_NODES 50000
#define N_EDGES 800000
#define IN_FEAT 1000
#define HID 128
#define HEADS 2
#define FOUT 256   /* HEADS*HID */
#define NEG_SLOPE 0.2f
#define EPS 1e-16f

#define KPAD 1024
#define GEMM_NWG 782        /* 391 row-panels x 2 col-blocks */

typedef __bf16 bf16x8 __attribute__((ext_vector_type(8)));
typedef float f32x4 __attribute__((ext_vector_type(4)));

__device__ __forceinline__ float lrelu(float v) { return v > 0.f ? v : NEG_SLOPE * v; }

__device__ __forceinline__ ushort bf16rn(float v) {
  union { float f; unsigned u; } a; a.f = v;
  unsigned r = a.u + 0x7FFFu + ((a.u >> 16) & 1u);
  return (ushort)(r >> 16);
}

__device__ __forceinline__ void gload_lds16(const void* g, void* l) {
  __builtin_amdgcn_global_load_lds((const __attribute__((address_space(1))) void*)g,
                                   (__attribute__((address_space(3))) void*)l, 16, 0, 0);
}

// ---------------- CSR build ----------------
__global__ void hist_kernel(const int* __restrict__ dst, int* __restrict__ counts) {
  int e = blockIdx.x * blockDim.x + threadIdx.x;
  if (e < N_EDGES) atomicAdd(&counts[dst[e]], 1);
}

__global__ __launch_bounds__(1024) void scan1_kernel(const int* __restrict__ counts,
                                                     int* __restrict__ iscan,
                                                     int* __restrict__ bsum) {
  __shared__ int buf[1024];
  const int t = threadIdx.x;
  const int i = blockIdx.x * 1024 + t;
  int v = (i < N_NODES) ? counts[i] : 0;
  buf[t] = v;
  __syncthreads();
#pragma unroll
  for (int off = 1; off < 1024; off <<= 1) {
    int x = (t >= off) ? buf[t - off] : 0;
    __syncthreads();
    buf[t] += x;
    __syncthreads();
  }
  if (i < N_NODES) iscan[i] = buf[t];
  if (t == 1023) bsum[blockIdx.x] = buf[1023];
}

__global__ __launch_bounds__(64) void scan2_kernel(const int* __restrict__ bsum,
                                                   int* __restrict__ boff,
                                                   int* __restrict__ row_start, int nblk) {
  const int t = threadIdx.x;
  int v = (t < nblk) ? bsum[t] : 0;
  int s = v;
#pragma unroll
  for (int off = 1; off < 64; off <<= 1) {
    int y = __shfl_up(s, off, 64);
    if (t >= off) s += y;
  }
  if (t < nblk) boff[t] = s - v;
  if (t == nblk - 1) row_start[N_NODES] = s;
}

__global__ void scan3_kernel(const int* __restrict__ iscan, const int* __restrict__ counts,
                             const int* __restrict__ boff, int* __restrict__ row_start,
                             int* __restrict__ cursor) {
  int i = blockIdx.x * blockDim.x + threadIdx.x;
  if (i < N_NODES) {
    int rs = boff[i >> 10] + iscan[i] - counts[i];
    row_start[i] = rs;
    cursor[i] = rs;
  }
}

__global__ void scatter_kernel(const int* __restrict__ src, const int* __restrict__ dst,
                               int* __restrict__ cursor, int* __restrict__ csr_src) {
  int e = blockIdx.x * blockDim.x + threadIdx.x;
  if (e < N_EDGES) {
    int pos = atomicAdd(&cursor[dst[e]], 1);
    csr_src[pos] = src[e];
  }
}

// B: W1[1000][256] f32 -> Bt [256][KPAD] bf16 round-nearest (transposed, zero-padded)
__global__ __launch_bounds__(256) void cvtB1_kernel(const float* __restrict__ B,
                                                    ushort* __restrict__ Bt) {
  int i = blockIdx.x * 256 + threadIdx.x;   // 0..65535
  int nn = i >> 8;
  int k4 = (i & 255) << 2;
  ushort4 h;
#pragma unroll
  for (int j = 0; j < 4; ++j) {
    int k = k4 + j;
    float v = (k < IN_FEAT) ? B[(size_t)k * FOUT + nn] : 0.f;
    ((ushort*)&h)[j] = bf16rn(v);
  }
  *(ushort4*)(Bt + (size_t)nn * KPAD + k4) = h;
}

// ---------------- GEMM: h1 = x @ W1, A split-bf16 in-register, B single bf16 ----------------
// BM=128 x BN=128 per block; 4 waves, each 32 rows x 128 cols.
// A: direct global f32 loads per fragment (no LDS). B: LDS double-buffered, XOR-swizzled.
__global__ __launch_bounds__(256, 2) void gemm_fused2_kernel(
    const float* __restrict__ X, const ushort* __restrict__ Bt,
    float* __restrict__ C) {
  __shared__ ushort lB[2][128 * 64];

  // bijective XCD swizzle (m204); keeps a row-panel's 2 col-blocks on one XCD
  const int orig = blockIdx.x;
  const int q = GEMM_NWG >> 3, r = GEMM_NWG & 7;
  const int xcd = orig & 7, idx = orig >> 3;
  const int lin = (xcd < r) ? xcd * (q + 1) + idx : r * (q + 1) + (xcd - r) * q + idx;
  const int brow = (lin >> 1) * 128;
  const int bcol = (lin & 1) * 128;

  const int t = threadIdx.x;
  const int lane = t & 63, wid = t >> 6;
  const int fr = lane & 15, g = lane >> 4;
  const int wrow = wid * 32;

  float4 areg[2][2][2];  // [m][h][half]; lanes l and l+16 share a 64B line

  auto loadA = [&](int ks) {
#pragma unroll
    for (int m = 0; m < 2; ++m)
#pragma unroll
      for (int h = 0; h < 2; ++h) {
        const int row = brow + wrow + m * 16 + fr;
        const int k = ks * 64 + h * 32 + g * 8;
        if (row < N_NODES && k < IN_FEAT) {  // 1000%8==0: never partial
          const float* p = X + (size_t)row * IN_FEAT + k;
          areg[m][h][0] = *(const float4*)p;
          areg[m][h][1] = *(const float4*)(p + 4);
        } else {
          areg[m][h][0] = make_float4(0.f, 0.f, 0.f, 0.f);
          areg[m][h][1] = make_float4(0.f, 0.f, 0.f, 0.f);
        }
      }
  };

  auto stageB = [&](int ks, int buf) {
    const int k0b = ks * 128;
#pragma unroll
    for (int i = 0; i < 4; ++i) {
      int u = i * 256 + t;
      int row = u >> 3;
      int inner = (u & 7) * 16;
      int soff = inner ^ ((row & 7) << 4);  // inverse-swizzled source, linear dest
      size_t boff = (size_t)(bcol + row) * (KPAD * 2) + k0b + soff;
      gload_lds16((const char*)Bt + boff, (char*)&lB[buf][0] + u * 16);
    }
  };

  f32x4 acc[2][8];
  const f32x4 z4 = {0.f, 0.f, 0.f, 0.f};
#pragma unroll
  for (int m = 0; m < 2; ++m)
#pragma unroll
    for (int n = 0; n < 8; ++n) acc[m][n] = z4;

  stageB(0, 0);
  loadA(0);
  const int NK = KPAD / 64;  // 16
  for (int ks = 0; ks < NK; ++ks) {
    // in-register trunc-split of this tile's A (auto-waits the A loads)
    bf16x8 ah[2][2], al[2][2];
#pragma unroll
    for (int m = 0; m < 2; ++m)
#pragma unroll
      for (int h = 0; h < 2; ++h) {
        const float* vv = (const float*)&areg[m][h][0];
        bf16x8 hv, lv;
#pragma unroll
        for (int j = 0; j < 8; ++j) {
          float v = vv[j];
          unsigned u = __float_as_uint(v);
          ((ushort*)&hv)[j] = (ushort)(u >> 16);
          float hf = __uint_as_float(u & 0xFFFF0000u);
          float d = v - hf;
          ((ushort*)&lv)[j] = (ushort)(__float_as_uint(d) >> 16);
        }
        ah[m][h] = hv;
        al[m][h] = lv;
      }
    // prefetch next A; counted vmcnt drains ONLY the older stageB(ks) ops
    if (ks + 1 < NK) {
      loadA(ks + 1);  // 8 load instrs, stay in flight across the barrier
      asm volatile("s_waitcnt vmcnt(8)" ::: "memory");
    } else {
      asm volatile("s_waitcnt vmcnt(0)" ::: "memory");
    }
    __builtin_amdgcn_sched_barrier(0);
    __builtin_amdgcn_s_barrier();   // tile ks visible in lB[ks&1]; prev readers done
    __builtin_amdgcn_sched_barrier(0);
    if (ks + 1 < NK) stageB(ks + 1, (ks + 1) & 1);  // slot freed by the barrier
    const int buf = ks & 1;
#pragma unroll
    for (int h = 0; h < 2; ++h) {
      bf16x8 bfrag[8];
#pragma unroll
      for (int n = 0; n < 8; ++n) {
        int row = n * 16 + fr;
        int off = row * 128 + ((h * 64 + g * 16) ^ ((row & 7) << 4));
        bfrag[n] = *(const bf16x8*)((const char*)&lB[buf][0] + off);
      }
#pragma unroll
      for (int m = 0; m < 2; ++m)
#pragma unroll
        for (int n = 0; n < 8; ++n) {
          acc[m][n] = __builtin_amdgcn_mfma_f32_16x16x32_bf16(ah[m][h], bfrag[n], acc[m][n], 0, 0, 0);
          acc[m][n] = __builtin_amdgcn_mfma_f32_16x16x32_bf16(al[m][h], bfrag[n], acc[m][n], 0, 0, 0);
        }
    }
  }

  // C/D layout: col = lane&15, row = (lane>>4)*4 + reg  [m89-verified]
#pragma unroll
  for (int m = 0; m < 2; ++m) {
    int rowbase = brow + wrow + m * 16 + g * 4;
#pragma unroll
    for (int n = 0; n < 8; ++n) {
      int col = bcol + n * 16 + fr;
#pragma unroll
      for (int rr = 0; rr < 4; ++rr) {
        int row = rowbase + rr;
        if (row < N_NODES) C[(size_t)row * FOUT + col] = acc[m][n][rr];
      }
    }
  }
}

// ---------------- attention logits per node ----------------
__global__ __launch_bounds__(64) void att1_kernel(const float* __restrict__ h1,
                                                  const float* __restrict__ as,
                                                  const float* __restrict__ ad,
                                                  float* __restrict__ asrc,
                                                  float* __restrict__ adst) {
  const int n = blockIdx.x;
  const int lane = threadIdx.x;
  const float* hr = h1 + (size_t)n * FOUT;
  float4 hv = *(const float4*)(hr + 4 * lane);
  float4 sv = *(const float4*)(as + 4 * lane);
  float4 dv = *(const float4*)(ad + 4 * lane);
  float ps = hv.x * sv.x + hv.y * sv.y + hv.z * sv.z + hv.w * sv.w;
  float pd = hv.x * dv.x + hv.y * dv.y + hv.z * dv.z + hv.w * dv.w;
#pragma unroll
  for (int off = 16; off > 0; off >>= 1) {  // reduce within each 32-lane half
    ps += __shfl_xor(ps, off, 64);
    pd += __shfl_xor(pd, off, 64);
  }
  if ((lane & 31) == 0) {
    int hh = lane >> 5;
    asrc[2 * n + hh] = ps;
    adst[2 * n + hh] = pd;
  }
}

// ---------------- layer-1 agg: wave-parallel softmax + gather, fused relu+W2 dot -> z ----------------
__global__ __launch_bounds__(64) void agg1_kernel(
    const float* __restrict__ h1, const float* __restrict__ asrc,
    const float* __restrict__ adst, const int* __restrict__ row_start,
    const int* __restrict__ csr_src, const float* __restrict__ b1,
    const float* __restrict__ W2, float* __restrict__ z) {
  const int n = blockIdx.x;
  const int lane = threadIdx.x;
  const bool head0 = lane < 32;
  const float ad0 = adst[2 * n], ad1 = adst[2 * n + 1];
  const int jb = row_start[n], je = row_start[n + 1];
  float ax = 0.f, ay = 0.f, az = 0.f, aw = 0.f;
  float m0 = -INFINITY, m1 = -INFINITY, s0 = 0.f, s1 = 0.f;

  for (int base = jb; base < je; base += 64) {
    int cnt = je - base;
    if (cnt > 64) cnt = 64;
    const bool act = lane < cnt;
    const int sr = csr_src[base + (act ? lane : 0)];
    float e0 = -INFINITY, e1 = -INFINITY;
    if (act) {
      const float2 av = *(const float2*)(asrc + 2 * sr);
      e0 = lrelu(av.x + ad0);
      e1 = lrelu(av.y + ad1);
    }
    float c0 = e0, c1 = e1;
#pragma unroll
    for (int off = 32; off > 0; off >>= 1) {
      c0 = fmaxf(c0, __shfl_xor(c0, off, 64));
      c1 = fmaxf(c1, __shfl_xor(c1, off, 64));
    }
    const float m0n = fmaxf(m0, c0), m1n = fmaxf(m1, c1);
    const float f0 = __expf(m0 - m0n), f1 = __expf(m1 - m1n);  // exp(-inf)=0 first chunk
    const float p0 = act ? __expf(e0 - m0n) : 0.f;
    const float p1 = act ? __expf(e1 - m1n) : 0.f;
    float t0 = p0, t1 = p1;
#pragma unroll
    for (int off = 32; off > 0; off >>= 1) {
      t0 += __shfl_xor(t0, off, 64);
      t1 += __shfl_xor(t1, off, 64);
    }
    s0 = s0 * f0 + t0;
    s1 = s1 * f1 + t1;
    m0 = m0n;
    m1 = m1n;
    const float f = head0 ? f0 : f1;
    ax *= f; ay *= f; az *= f; aw *= f;
    for (int j = 0; j < cnt; ++j) {
      const int srj = __shfl(sr, j, 64);
      const float pj0 = __shfl(p0, j, 64);
      const float pj1 = __shfl(p1, j, 64);
      const float pj = head0 ? pj0 : pj1;
      float4 hv = *(const float4*)(h1 + (size_t)srj * FOUT + 4 * lane);
      ax = fmaf(pj, hv.x, ax);
      ay = fmaf(pj, hv.y, ay);
      az = fmaf(pj, hv.z, az);
      aw = fmaf(pj, hv.w, aw);
    }
  }
  const float inv = head0 ? 1.f / (s0 + EPS) : 1.f / (s1 + EPS);
  float4 bv = *(const float4*)(b1 + 4 * lane);
  float4 wv = *(const float4*)(W2 + 4 * lane);
  float r0 = fmaxf(fmaf(ax, inv, bv.x), 0.f);
  float r1 = fmaxf(fmaf(ay, inv, bv.y), 0.f);
  float r2 = fmaxf(fmaf(az, inv, bv.z), 0.f);
  float r3 = fmaxf(fmaf(aw, inv, bv.w), 0.f);
  float part = r0 * wv.x + r1 * wv.y + r2 * wv.z + r3 * wv.w;
#pragma unroll
  for (int off = 32; off > 0; off >>= 1) part += __shfl_xor(part, off, 64);
  if (lane == 0) z[n] = part;
}

// ---------------- layer-2 GAT (scalar features), wave-parallel ----------------
__global__ __launch_bounds__(64) void agg2_kernel(
    const float* __restrict__ z, const int* __restrict__ row_start,
    const int* __restrict__ csr_src, const float* __restrict__ as2p,
    const float* __restrict__ ad2p, const float* __restrict__ b2p,
    float* __restrict__ out2) {
  const int n = blockIdx.x;
  const int lane = threadIdx.x;
  const float as2 = as2p[0], ad2 = ad2p[0], b2 = b2p[0];
  const float adz = z[n] * ad2;
  const int jb = row_start[n], je = row_start[n + 1];
  float m = -INFINITY, s = 0.f, num = 0.f;
  for (int base = jb; base < je; base += 64) {
    int cnt = je - base;
    if (cnt > 64) cnt = 64;
    const bool act = lane < cnt;
    const int sr = csr_src[base + (act ? lane : 0)];
    const float zs = act ? z[sr] : 0.f;
    const float e = act ? lrelu(zs * as2 + adz) : -INFINITY;
    float c = e;
#pragma unroll
    for (int off = 32; off > 0; off >>= 1) c = fmaxf(c, __shfl_xor(c, off, 64));
    const float mn = fmaxf(m, c);
    const float f = __expf(m - mn);
    const float p = act ? __expf(e - mn) : 0.f;
    float tp = p, tz = p * zs;
#pragma unroll
    for (int off = 32; off > 0; off >>= 1) {
      tp += __shfl_xor(tp, off, 64);
      tz += __shfl_xor(tz, off, 64);
    }
    s = s * f + tp;
    num = num * f + tz;
    m = mn;
  }
  if (lane == 0) out2[n] = num / (s + EPS) + b2;
}

__global__ void readout_kernel(const float* __restrict__ out2, const int* __restrict__ ridx,
                               float* __restrict__ out, int n) {
  int i = blockIdx.x * blockDim.x + threadIdx.x;
  if (i < n) out[i] = out2[ridx[i]];
}

extern "C" void kernel_launch(void* const* d_in, const int* in_sizes, int n_in,
                              void* d_out, int out_size, void* d_ws, size_t ws_size,
                              hipStream_t stream) {
  const float* x   = (const float*)d_in[0];
  const int* ei    = (const int*)d_in[1];
  const int* ridx  = (const int*)d_in[2];
  const float* W1  = (const float*)d_in[3];
  const float* as1 = (const float*)d_in[4];
  const float* ad1 = (const float*)d_in[5];
  const float* b1  = (const float*)d_in[6];
  const float* W2  = (const float*)d_in[7];
  const float* as2 = (const float*)d_in[8];
  const float* ad2 = (const float*)d_in[9];
  const float* b2  = (const float*)d_in[10];
  float* out = (float*)d_out;

  char* ws = (char*)d_ws;
  size_t off = 0;
  auto alloc = [&](size_t bytes) -> void* {
    void* p = ws + off;
    off += (bytes + 255) & ~(size_t)255;
    return p;
  };
  float* h1   = (float*)alloc((size_t)N_NODES * FOUT * 4);
  float* asrc = (float*)alloc((size_t)N_NODES * 2 * 4);
  float* adst = (float*)alloc((size_t)N_NODES * 2 * 4);
  float* z    = (float*)alloc((size_t)N_NODES * 4);
  float* out2 = (float*)alloc((size_t)N_NODES * 4);
  int* counts = (int*)alloc((size_t)N_NODES * 4);
  int* rowst  = (int*)alloc((size_t)(N_NODES + 1) * 4);
  int* cursor = (int*)alloc((size_t)N_NODES * 4);
  int* csr    = (int*)alloc((size_t)N_EDGES * 4);
  int* iscan  = (int*)alloc((size_t)N_NODES * 4);
  int* bsum   = (int*)alloc(64 * 4);
  int* boff   = (int*)alloc(64 * 4);
  ushort* Bt  = (ushort*)alloc((size_t)FOUT * KPAD * 2);

  const int* src = ei;
  const int* dst = ei + N_EDGES;
  const int nblk = (N_NODES + 1023) / 1024;  // 49

  hipMemsetAsync(counts, 0, (size_t)N_NODES * 4, stream);
  hist_kernel<<<(N_EDGES + 255) / 256, 256, 0, stream>>>(dst, counts);
  scan1_kernel<<<nblk, 1024, 0, stream>>>(counts, iscan, bsum);
  scan2_kernel<<<1, 64, 0, stream>>>(bsum, boff, rowst, nblk);
  scan3_kernel<<<(N_NODES + 255) / 256, 256, 0, stream>>>(iscan, counts, boff, rowst, cursor);
  scatter_kernel<<<(N_EDGES + 255) / 256, 256, 0, stream>>>(src, dst, cursor, csr);

  cvtB1_kernel<<<256, 256, 0, stream>>>(W1, Bt);
  gemm_fused2_kernel<<<GEMM_NWG, 256, 0, stream>>>(x, Bt, h1);

  att1_kernel<<<N_NODES, 64, 0, stream>>>(h1, as1, ad1, asrc, adst);
  agg1_kernel<<<N_NODES, 64, 0, stream>>>(h1, asrc, adst, rowst, csr, b1, W2, z);
  agg2_kernel<<<N_NODES, 64, 0, stream>>>(z, rowst, csr, as2, ad2, b2, out2);
  readout_kernel<<<4, 256, 0, stream>>>(out2, ridx, out, out_size);
}